// Round 8
// baseline (314.977 us; speedup 1.0000x reference)
//
#include <hip/hip_runtime.h>

#define NN 2
#define LL 4096
#define HH 12
#define DD 64
#define HD_ 768
#define M_TOT (NN * LL)   // 8192
#define KVSTRIDE 262144   // elems per (n,h) in pre-permuted K'/V' layouts

typedef __bf16 bf16_t;
typedef _Float16 f16_t;
typedef __bf16 bf16x8 __attribute__((ext_vector_type(8)));
typedef __bf16 bf16x4 __attribute__((ext_vector_type(4)));
typedef _Float16 f16x2 __attribute__((ext_vector_type(2)));
typedef _Float16 f16x4 __attribute__((ext_vector_type(4)));
typedef _Float16 f16x8 __attribute__((ext_vector_type(8)));
typedef float floatx4 __attribute__((ext_vector_type(4)));
typedef float floatx16 __attribute__((ext_vector_type(16)));

// softmax prescale folded into Q at the QKV GEMM: 1/sqrt(64) * log2(e)
#define QSCALE 0.1803368801111f

__device__ __forceinline__ void async_load16(const void* g, void* l) {
    __builtin_amdgcn_global_load_lds(
        (const __attribute__((address_space(1))) unsigned int*)(g),
        (__attribute__((address_space(3))) unsigned int*)(l),
        16, 0, 0);
}

__device__ __forceinline__ f16x2 pkrtz(float a, float b) {
    return __builtin_bit_cast(f16x2, __builtin_amdgcn_cvt_pkrtz(a, b));
}

// ---------------- fused prep: fp32->bf16 x convert + W^T transpose ---------
struct PrepArgs { const float* x; bf16_t* xb; const float* W[4]; bf16_t* Wt[4]; };
#define CVT_BLOCKS 6144   // M_TOT*HD_/4/256
__global__ __launch_bounds__(256) void prep_kernel(PrepArgs a) {
    __shared__ bf16_t T[64 * 65];
    const int bid = blockIdx.x;
    const int tid = threadIdx.x;
    if (bid < CVT_BLOCKS) {
        const int i = bid * 256 + tid;
        const float4 v = ((const float4*)a.x)[i];
        bf16_t* d = a.xb + (size_t)i * 4;
        d[0] = (bf16_t)v.x; d[1] = (bf16_t)v.y; d[2] = (bf16_t)v.z; d[3] = (bf16_t)v.w;
        return;
    }
    int r = bid - CVT_BLOCKS;          // 0..575
    const int z = r / 144; r -= z * 144;
    const int k0 = (r / 12) * 64, n0 = (r % 12) * 64;
    {
        const int k = tid >> 2;
        const int nc = (tid & 3) * 16;
        const float* src = a.W[z] + (size_t)(k0 + k) * HD_ + n0 + nc;
        for (int i = 0; i < 4; ++i) {
            float4 v = *(const float4*)(src + i * 4);
            T[(nc + i * 4 + 0) * 65 + k] = (bf16_t)v.x;
            T[(nc + i * 4 + 1) * 65 + k] = (bf16_t)v.y;
            T[(nc + i * 4 + 2) * 65 + k] = (bf16_t)v.z;
            T[(nc + i * 4 + 3) * 65 + k] = (bf16_t)v.w;
        }
    }
    __syncthreads();
    {
        const int n = tid >> 2;
        const int kc = (tid & 3) * 16;
        bf16_t* dst = a.Wt[z] + (size_t)(n0 + n) * HD_ + k0 + kc;
        bf16x8 v0, v1;
        for (int j = 0; j < 8; ++j) { v0[j] = T[n * 65 + kc + j]; v1[j] = T[n * 65 + kc + 8 + j]; }
        *(bf16x8*)dst = v0;
        *(bf16x8*)(dst + 8) = v1;
    }
}

// ---------------- m97-style 128x128 GEMM tile core (single-buffered) -------
__device__ __forceinline__ void gemm_tile128(
    const bf16_t* __restrict__ A, const bf16_t* __restrict__ Bt,
    bf16_t* As, bf16_t* Bs, int m0, int n0, floatx4 (&acc)[4][4])
{
    const int tid  = threadIdx.x;
    const int w    = tid >> 6, lane = tid & 63;
    const int quad = lane >> 4, l16 = lane & 15;
    const int wm = w >> 1, wn = w & 1;
    const int rsub = lane >> 3;
    const int csub = (lane & 7) * 8;

    const bf16_t* aBase = A + (size_t)(m0 + w * 32 + rsub) * HD_ + csub;
    const bf16_t* bBase = Bt + (size_t)(n0 + w * 32 + rsub) * HD_ + csub;

    for (int kt = 0; kt < HD_; kt += 64) {
        __syncthreads();
        for (int i = 0; i < 4; ++i) {
            const int ar = w * 32 + i * 8;
            async_load16(aBase + (size_t)i * 8 * HD_ + kt, As + ar * 64 + lane * 8);
            async_load16(bBase + (size_t)i * 8 * HD_ + kt, Bs + ar * 64 + lane * 8);
        }
        __syncthreads();
        for (int ks = 0; ks < 2; ++ks) {
            bf16x8 af[4], bf[4];
            for (int mi = 0; mi < 4; ++mi)
                af[mi] = *(const bf16x8*)&As[(wm * 64 + mi * 16 + l16) * 64 + ks * 32 + quad * 8];
            for (int ni = 0; ni < 4; ++ni)
                bf[ni] = *(const bf16x8*)&Bs[(wn * 64 + ni * 16 + l16) * 64 + ks * 32 + quad * 8];
            for (int mi = 0; mi < 4; ++mi)
                for (int ni = 0; ni < 4; ++ni)
                    acc[mi][ni] = __builtin_amdgcn_mfma_f32_16x16x32_bf16(
                        af[mi], bf[ni], acc[mi][ni], 0, 0, 0);
        }
    }
}

// ---------------- fused QKV projection (z = 0:Q, 1:K, 2:V) -----------------
// K' layout: nh | kvb=l>>5 | s=d>>4 | (l&31)+32*((d>>3)&1) | d&7
// V' layout (kv bits 2<->3 swapped so P needs no lane shuffles):
//   nh | (l>>6)*2+(d>>5) | (l>>4)&3 | (d&31)+32*((l>>2)&1) | (l&3)+4*((l>>3)&1)
// Single-buffered staging kept: 4.5 blocks/CU provides the TLP that hides
// the per-k-step barrier drain (dbuf here would cost 12->8 waves/CU, m132).
struct QKVArgs {
    const bf16_t* Bt[3];
    const float* bias[3];
    void* out[3];
};
__global__ __launch_bounds__(256) void gemm_qkv_kernel(const bf16_t* __restrict__ A, QKVArgs p)
{
    __shared__ __align__(16) bf16_t S[2 * 128 * 64];   // As | Bs, reused as out-stage
    const int z = blockIdx.z;
    const int m0 = blockIdx.y * 128, n0 = blockIdx.x * 128;

    floatx4 acc[4][4] = {};
    gemm_tile128(A, p.Bt[z], S, S + 8192, m0, n0, acc);

    const int tid  = threadIdx.x;
    const int lane = tid & 63;
    const int quad = lane >> 4, l16 = lane & 15;
    const int w    = tid >> 6;
    const int wm = w >> 1, wn = w & 1;
    const float scale = (z == 0) ? QSCALE : 1.0f;
    const float* bias = p.bias[z];

    __syncthreads();   // all waves done reading As/Bs
    for (int ni = 0; ni < 4; ++ni) {
        const int dl = ni * 16 + l16;
        const float bv = bias[n0 + wn * 64 + dl];
        for (int mi = 0; mi < 4; ++mi) {
            for (int r = 0; r < 4; ++r) {
                const int ll = wm * 64 + mi * 16 + quad * 4 + r;
                const float val = (acc[mi][ni][r] + bv) * scale;
                int off;
                if (z == 0)
                    off = ll * 64 + dl;
                else if (z == 1)
                    off = ((ll >> 5) * 4 + (dl >> 4)) * 512
                        + ((ll & 31) + 32 * ((dl >> 3) & 1)) * 8 + (dl & 7);
                else
                    off = (((ll >> 6) * 2 + (dl >> 5)) * 4 + ((ll >> 4) & 3)) * 512
                        + ((dl & 31) + 32 * ((ll >> 2) & 1)) * 8
                        + ((ll & 3) + 4 * ((ll >> 3) & 1));
                if (z == 2) ((f16_t*)S)[wn * 8192 + off] = (f16_t)val;
                else        S[wn * 8192 + off] = (bf16_t)val;
            }
        }
    }
    __syncthreads();

    // copy out: 16 KB per head, fully contiguous in global
    const int ht = tid >> 7, idx = tid & 127;
    const int nn = m0 >> 12, l0 = m0 & 4095;
    const int h = (n0 >> 6) + ht;
    char* dstBase;
    if (z == 0)
        dstBase = (char*)p.out[0] + (((size_t)(nn * HH + h) * LL + l0) * 64) * 2;
    else if (z == 1)
        dstBase = (char*)p.out[1] + ((size_t)(nn * HH + h) * KVSTRIDE + (size_t)(l0 >> 5) * 2048) * 2;
    else
        dstBase = (char*)p.out[2] + ((size_t)(nn * HH + h) * KVSTRIDE + (size_t)(l0 >> 6) * 4096) * 2;
    const bf16_t* srcB = S + ht * 8192;
    for (int c = 0; c < 8; ++c) {
        const int cc = (c + idx) & 7;   // bank-rotated: conflict-minimal b128 reads
        *(bf16x8*)(dstBase + (idx * 64 + cc * 8) * 2) = *(const bf16x8*)(srcB + idx * 64 + cc * 8);
    }
}

// ---------------- output projection (fp32 out), 128x128 + LDS dbuf ---------
// Grid is only 384 blocks = 1.5 blocks/CU: half the CUs hold ONE block, so
// the 2-barrier k-loop's staging drain has no TLP to hide it. Fix: double-
// buffered 2-phase staging (one __syncthreads per k-step; stage(t+1) issued
// after the barrier, landing under compute(t) -- the R1-validated pattern).
// dbuf LDS = 64 KB caps at 2 blocks/CU, but the grid supplies only 1.5, so
// the LDS cost is free; within-block overlap replaces the missing TLP.
__global__ __launch_bounds__(256) void gemm_o_kernel(
    const bf16_t* __restrict__ A, const bf16_t* __restrict__ Bt,
    const float* __restrict__ bias, float* __restrict__ Cout)
{
    __shared__ __align__(16) bf16_t As[2][128 * 64];   // 32 KB
    __shared__ __align__(16) bf16_t Bs[2][128 * 64];   // 32 KB
    const int m0 = blockIdx.y * 128, n0 = blockIdx.x * 128;

    const int tid  = threadIdx.x;
    const int w    = tid >> 6, lane = tid & 63;
    const int quad = lane >> 4, l16 = lane & 15;
    const int wm = w >> 1, wn = w & 1;
    const int rsub = lane >> 3;
    const int csub = (lane & 7) * 8;

    const bf16_t* aBase = A + (size_t)(m0 + w * 32 + rsub) * HD_ + csub;
    const bf16_t* bBase = Bt + (size_t)(n0 + w * 32 + rsub) * HD_ + csub;

    floatx4 acc[4][4] = {};

#define OSTAGE(buf, kt)                                                       \
    _Pragma("unroll")                                                         \
    for (int i = 0; i < 4; ++i) {                                             \
        const int ar = w * 32 + i * 8;                                        \
        async_load16(aBase + (size_t)i * 8 * HD_ + (kt), &As[buf][ar * 64 + lane * 8]); \
        async_load16(bBase + (size_t)i * 8 * HD_ + (kt), &Bs[buf][ar * 64 + lane * 8]); \
    }

    // prologue: stage k-step 0 into buffer 0
    OSTAGE(0, 0)

    int cur = 0;
    for (int kt = 0; kt < HD_; kt += 64, cur ^= 1) {
        // drains this wave's buf[cur] DMAs (vmcnt(0)) + rendezvous: no wave
        // still reads buf[cur^1] (its compute finished before this barrier)
        __syncthreads();
        if (kt + 64 < HD_) OSTAGE(cur ^ 1, kt + 64)   // lands under compute(cur)

        #pragma unroll
        for (int ks = 0; ks < 2; ++ks) {
            bf16x8 af[4], bf[4];
            #pragma unroll
            for (int mi = 0; mi < 4; ++mi)
                af[mi] = *(const bf16x8*)&As[cur][(wm * 64 + mi * 16 + l16) * 64 + ks * 32 + quad * 8];
            #pragma unroll
            for (int ni = 0; ni < 4; ++ni)
                bf[ni] = *(const bf16x8*)&Bs[cur][(wn * 64 + ni * 16 + l16) * 64 + ks * 32 + quad * 8];
            #pragma unroll
            for (int mi = 0; mi < 4; ++mi)
                #pragma unroll
                for (int ni = 0; ni < 4; ++ni)
                    acc[mi][ni] = __builtin_amdgcn_mfma_f32_16x16x32_bf16(
                        af[mi], bf[ni], acc[mi][ni], 0, 0, 0);
        }
    }
#undef OSTAGE

    #pragma unroll
    for (int ni = 0; ni < 4; ++ni) {
        const int col = n0 + wn * 64 + ni * 16 + l16;
        const float bv = bias[col];
        #pragma unroll
        for (int mi = 0; mi < 4; ++mi)
            #pragma unroll
            for (int r = 0; r < 4; ++r) {
                const int row = m0 + wm * 64 + mi * 16 + quad * 4 + r;
                Cout[(size_t)row * HD_ + col] = acc[mi][ni][r] + bv;
            }
    }
}

// ---------------- flash attention: S(t+1) || P(t) double pipeline ----------
// (round-2 validated kernel: ~108-113 us, MfmaUtil 43-46, conflicts 147K,
// VGPR 80 -- confirmed 3x. Frozen.)
__global__ __launch_bounds__(256, 3) void attn_kernel(
    const bf16_t* __restrict__ qg, const bf16_t* __restrict__ kf,
    const f16_t* __restrict__ vf, bf16_t* __restrict__ og)
{
    __shared__ union {
        struct {
            bf16_t Ks[2][4096];   // 2 x 8 KB tiles
            f16_t  Vs[4][4096];   // 4 x 8 KB tiles
        } s;                      // 48 KB -> 3 blocks/CU
        bf16_t OT[128 * 72];      // epilogue (18 KB)
    } u;

    const int tid = threadIdx.x;
    const int w = tid >> 6, lane = tid & 63;
    const int l32 = lane & 31, hi = lane >> 5;

    // XCD-aware remap: 768 blocks = 8 XCDs x 96 (bijective). Each XCD owns
    // 3 consecutive nh -> its 3 MB KV working set stays L2-resident.
    const int lb = blockIdx.y * gridDim.x + blockIdx.x;
    const int idx = (lb & 7) * 96 + (lb >> 3);
    const int nh = idx >> 5;
    const int qt0 = (idx & 31) * 128;
    const int nIdx = nh / HH, hIdx = nh % HH;

    // Q B-frags: lane (q=l32, hi) holds Q[qrow][s*16 + hi*8 + j]
    bf16x8 qfrag[4];
    {
        const bf16_t* qp = qg + ((size_t)nh * LL + qt0 + w * 32 + l32) * DD + hi * 8;
        for (int s = 0; s < 4; ++s) qfrag[s] = *(const bf16x8*)(qp + s * 16);
    }

    // DMA: wave w stages chunks {2w, 2w+1} of each 8-chunk (8 KB) tile
    const bf16_t* ksrc = kf + (size_t)nh * KVSTRIDE + (2 * w) * 512 + lane * 8;
    const f16_t*  vsrc = vf + (size_t)nh * KVSTRIDE + (2 * w) * 512 + lane * 8;
    const int soff0 = (2 * w) * 512 + lane * 8;
    const int soff1 = (2 * w + 1) * 512 + lane * 8;

    floatx16 oacc[2] = {};
    float rs = 0.f;
    floatx16 sA0, sA1, sB0, sB1;   // QK accumulators, A/B alternate per step

#define STAGE_K(kb) { async_load16(ksrc, &u.s.Ks[kb][soff0]);                 \
                      async_load16(ksrc + 512, &u.s.Ks[kb][soff1]);           \
                      ksrc += 4096; }
#define STAGE_V(vb) { async_load16(vsrc, &u.s.Vs[vb][soff0]);                 \
                      async_load16(vsrc + 512, &u.s.Vs[vb][soff1]);           \
                      vsrc += 4096; }

// S: QK^T for one tile from K ring slot kr -> (SD0: kv rows 0..31, SD1: 32..63)
#define SSTEP(SD0, SD1, kr)                                                   \
    {                                                                         \
        SD0 = (floatx16){}; SD1 = (floatx16){};                               \
        _Pragma("unroll")                                                     \
        for (int s = 0; s < 4; ++s) {                                         \
            bf16x8 a0 = *(const bf16x8*)&u.s.Ks[kr][s * 512 + lane * 8];      \
            SD0 = __builtin_amdgcn_mfma_f32_32x32x16_bf16(a0, qfrag[s], SD0, 0, 0, 0); \
            bf16x8 a1 = *(const bf16x8*)&u.s.Ks[kr][(4 + s) * 512 + lane * 8]; \
            SD1 = __builtin_amdgcn_mfma_f32_32x32x16_bf16(a1, qfrag[s], SD1, 0, 0, 0); \
        }                                                                     \
    }

// P half: softmax (exp2, row-sum) + PV MFMA for one kvb half from V slot vp
#define PHALF(SC, vp, kvb)                                                    \
    _Pragma("unroll")                                                         \
    for (int sub = 0; sub < 2; ++sub) {                                       \
        float p[8];                                                           \
        _Pragma("unroll")                                                     \
        for (int i = 0; i < 8; ++i)                                           \
            p[i] = __builtin_amdgcn_exp2f(SC[sub * 8 + i]);                   \
        rs += ((p[0] + p[1]) + (p[2] + p[3])) + ((p[4] + p[5]) + (p[6] + p[7])); \
        f16x2 ab = pkrtz(p[0], p[1]), cd = pkrtz(p[2], p[3]);                 \
        f16x2 ef = pkrtz(p[4], p[5]), gh = pkrtz(p[6], p[7]);                 \
        f16x4 lo4 = __builtin_shufflevector(ab, cd, 0, 1, 2, 3);              \
        f16x4 hi4 = __builtin_shufflevector(ef, gh, 0, 1, 2, 3);              \
        f16x8 pf = __builtin_shufflevector(lo4, hi4, 0, 1, 2, 3, 4, 5, 6, 7); \
        const int kstep = (kvb) * 2 + sub;                                    \
        _Pragma("unroll")                                                     \
        for (int db = 0; db < 2; ++db) {                                      \
            f16x8 av = *(const f16x8*)&u.s.Vs[vp][(db * 4 + kstep) * 512 + lane * 8]; \
            oacc[db] = __builtin_amdgcn_mfma_f32_32x32x16_f16(av, pf, oacc[db], 0, 0, 0); \
        }                                                                     \
    }

// One pipeline step: barrier; issue DMA for tile t+2; S(t+1); P(t).
// doDMA/doS are 0/1 literals; all ring indices compile-time.
#define STEP(doDMA, kw, vw, doS, kr, SD0, SD1, SP0, SP1, vp)                  \
    __syncthreads();                                                          \
    if (doDMA) { STAGE_K(kw); STAGE_V(vw); }                                  \
    __builtin_amdgcn_s_setprio(1);                                            \
    if (doS) SSTEP(SD0, SD1, kr);                                             \
    PHALF(SP0, vp, 0)                                                         \
    PHALF(SP1, vp, 1)                                                         \
    __builtin_amdgcn_s_setprio(0);

    // prologue: stage tiles 0,1; compute S(0)
    STAGE_K(0) STAGE_V(0) STAGE_K(1) STAGE_V(1)
    __syncthreads();
    SSTEP(sA0, sA1, 0);

    // steady state: 15 groups of 4 steps; P(0)..P(59), DMA tiles 2..61
    for (int t = 0; t < 60; t += 4) {
        STEP(1, 0, 2, 1, 1, sB0, sB1, sA0, sA1, 0)   // DMA t+2->K0,V2; S(t+1)<-K1; P(t)<-V0
        STEP(1, 1, 3, 1, 0, sA0, sA1, sB0, sB1, 1)   // DMA t+3->K1,V3; S(t+2)<-K0; P(t+1)<-V1
        STEP(1, 0, 0, 1, 1, sB0, sB1, sA0, sA1, 2)   // DMA t+4->K0,V0; S(t+3)<-K1; P(t+2)<-V2
        STEP(1, 1, 1, 1, 0, sA0, sA1, sB0, sB1, 3)   // DMA t+5->K1,V1; S(t+4)<-K0; P(t+3)<-V3
    }
    // tail: t = 60..63 (DMA tiles 62,63; last S is S(63))
    STEP(1, 0, 2, 1, 1, sB0, sB1, sA0, sA1, 0)       // DMA 62->K0,V2; S(61); P(60)
    STEP(1, 1, 3, 1, 0, sA0, sA1, sB0, sB1, 1)       // DMA 63->K1,V3; S(62); P(61)
    STEP(0, 0, 0, 1, 1, sB0, sB1, sA0, sA1, 2)       //               S(63); P(62)
    STEP(0, 0, 0, 0, 0, sA0, sA1, sB0, sB1, 3)       //                      P(63)

#undef STEP
#undef PHALF
#undef SSTEP
#undef STAGE_K
#undef STAGE_V

    // full row sum per q: add the partner half-wave's partial
    rs += __shfl_xor(rs, 32);
    const float rinv = __builtin_amdgcn_rcpf(rs);

    // O^T -> O via LDS transpose, then coalesced store
    __syncthreads();
    for (int db = 0; db < 2; ++db)
        for (int g = 0; g < 4; ++g) {
            bf16x4 o4;
            for (int r = 0; r < 4; ++r)
                o4[r] = (bf16_t)(oacc[db][g * 4 + r] * rinv);
            // d = r + 8g + 4hi + 32db
            *(bf16x4*)&u.OT[(w * 32 + l32) * 72 + db * 32 + hi * 4 + g * 8] = o4;
        }
    __syncthreads();

    const int q = tid >> 1, hf = tid & 1;
    const bf16_t* src = &u.OT[q * 72 + hf * 32];
    bf16x8 r0 = *(const bf16x8*)(src + 0);
    bf16x8 r1 = *(const bf16x8*)(src + 8);
    bf16x8 r2 = *(const bf16x8*)(src + 16);
    bf16x8 r3 = *(const bf16x8*)(src + 24);
    bf16_t* dst = og + ((size_t)nIdx * LL + qt0 + q) * HD_ + hIdx * 64 + hf * 32;
    *(bf16x8*)(dst + 0)  = r0;
    *(bf16x8*)(dst + 8)  = r1;
    *(bf16x8*)(dst + 16) = r2;
    *(bf16x8*)(dst + 24) = r3;
}

extern "C" void kernel_launch(void* const* d_in, const int* in_sizes, int n_in,
                              void* d_out, int out_size, void* d_ws, size_t ws_size,
                              hipStream_t stream) {
    const float* x  = (const float*)d_in[0];
    const float* Wq = (const float*)d_in[1];
    const float* bq = (const float*)d_in[2];
    const float* Wk = (const float*)d_in[3];
    const float* bk = (const float*)d_in[4];
    const float* Wv = (const float*)d_in[5];
    const float* bv = (const float*)d_in[6];
    const float* Wo = (const float*)d_in[7];
    const float* bo = (const float*)d_in[8];

    char* ws = (char*)d_ws;
    const size_t xbytes = (size_t)M_TOT * HD_ * 2;
    const size_t wbytes = (size_t)HD_ * HD_ * 2;

    bf16_t* xb  = (bf16_t*)ws; ws += xbytes;
    bf16_t* wqt = (bf16_t*)ws; ws += wbytes;
    bf16_t* wkt = (bf16_t*)ws; ws += wbytes;
    bf16_t* wvt = (bf16_t*)ws; ws += wbytes;
    bf16_t* wot = (bf16_t*)ws; ws += wbytes;
    bf16_t* qb  = (bf16_t*)ws; ws += xbytes;
    bf16_t* kfb = (bf16_t*)ws; ws += xbytes;
    f16_t*  vfb = (f16_t*)ws;  ws += xbytes;
    bf16_t* ob  = (bf16_t*)ws; ws += xbytes;

    PrepArgs pa;
    pa.x = x; pa.xb = xb;
    pa.W[0] = Wq; pa.W[1] = Wk; pa.W[2] = Wv; pa.W[3] = Wo;
    pa.Wt[0] = wqt; pa.Wt[1] = wkt; pa.Wt[2] = wvt; pa.Wt[3] = wot;
    prep_kernel<<<CVT_BLOCKS + 576, 256, 0, stream>>>(pa);

    QKVArgs qa;
    qa.Bt[0] = wqt; qa.Bt[1] = wkt; qa.Bt[2] = wvt;
    qa.bias[0] = bq; qa.bias[1] = bk; qa.bias[2] = bv;
    qa.out[0] = qb; qa.out[1] = kfb; qa.out[2] = vfb;
    gemm_qkv_kernel<<<dim3(HD_ / 128, M_TOT / 128, 3), 256, 0, stream>>>(xb, qa);

    attn_kernel<<<dim3(LL / 128, NN * HH), 256, 0, stream>>>(qb, kfb, vfb, ob);

    gemm_o_kernel<<<dim3(HD_ / 128, M_TOT / 128), 256, 0, stream>>>(ob, wot, bo, (float*)d_out);
}

// Round 9
// 296.155 us; speedup vs baseline: 1.0636x; 1.0636x over previous
//
#include <hip/hip_runtime.h>

#define NN 2
#define LL 4096
#define HH 12
#define DD 64
#define HD_ 768
#define M_TOT (NN * LL)   // 8192
#define KVSTRIDE 262144   // elems per (n,h) in pre-permuted K'/V' layouts

typedef __bf16 bf16_t;
typedef _Float16 f16_t;
typedef __bf16 bf16x8 __attribute__((ext_vector_type(8)));
typedef __bf16 bf16x4 __attribute__((ext_vector_type(4)));
typedef _Float16 f16x2 __attribute__((ext_vector_type(2)));
typedef _Float16 f16x4 __attribute__((ext_vector_type(4)));
typedef _Float16 f16x8 __attribute__((ext_vector_type(8)));
typedef float floatx4 __attribute__((ext_vector_type(4)));
typedef float floatx16 __attribute__((ext_vector_type(16)));

// softmax prescale folded into Q at the QKV GEMM: 1/sqrt(64) * log2(e)
#define QSCALE 0.1803368801111f

__device__ __forceinline__ void async_load16(const void* g, void* l) {
    __builtin_amdgcn_global_load_lds(
        (const __attribute__((address_space(1))) unsigned int*)(g),
        (__attribute__((address_space(3))) unsigned int*)(l),
        16, 0, 0);
}

__device__ __forceinline__ f16x2 pkrtz(float a, float b) {
    return __builtin_bit_cast(f16x2, __builtin_amdgcn_cvt_pkrtz(a, b));
}

// ---------------- fused prep: fp32->bf16 x convert + W^T transpose ---------
struct PrepArgs { const float* x; bf16_t* xb; const float* W[4]; bf16_t* Wt[4]; };
#define CVT_BLOCKS 6144   // M_TOT*HD_/4/256
__global__ __launch_bounds__(256) void prep_kernel(PrepArgs a) {
    __shared__ bf16_t T[64 * 65];
    const int bid = blockIdx.x;
    const int tid = threadIdx.x;
    if (bid < CVT_BLOCKS) {
        const int i = bid * 256 + tid;
        const float4 v = ((const float4*)a.x)[i];
        bf16_t* d = a.xb + (size_t)i * 4;
        d[0] = (bf16_t)v.x; d[1] = (bf16_t)v.y; d[2] = (bf16_t)v.z; d[3] = (bf16_t)v.w;
        return;
    }
    int r = bid - CVT_BLOCKS;          // 0..575
    const int z = r / 144; r -= z * 144;
    const int k0 = (r / 12) * 64, n0 = (r % 12) * 64;
    {
        const int k = tid >> 2;
        const int nc = (tid & 3) * 16;
        const float* src = a.W[z] + (size_t)(k0 + k) * HD_ + n0 + nc;
        for (int i = 0; i < 4; ++i) {
            float4 v = *(const float4*)(src + i * 4);
            T[(nc + i * 4 + 0) * 65 + k] = (bf16_t)v.x;
            T[(nc + i * 4 + 1) * 65 + k] = (bf16_t)v.y;
            T[(nc + i * 4 + 2) * 65 + k] = (bf16_t)v.z;
            T[(nc + i * 4 + 3) * 65 + k] = (bf16_t)v.w;
        }
    }
    __syncthreads();
    {
        const int n = tid >> 2;
        const int kc = (tid & 3) * 16;
        bf16_t* dst = a.Wt[z] + (size_t)(n0 + n) * HD_ + k0 + kc;
        bf16x8 v0, v1;
        for (int j = 0; j < 8; ++j) { v0[j] = T[n * 65 + kc + j]; v1[j] = T[n * 65 + kc + 8 + j]; }
        *(bf16x8*)dst = v0;
        *(bf16x8*)(dst + 8) = v1;
    }
}

// ---------------- m97-style 128x128 GEMM tile core (single-buffered) -------
__device__ __forceinline__ void gemm_tile128(
    const bf16_t* __restrict__ A, const bf16_t* __restrict__ Bt,
    bf16_t* As, bf16_t* Bs, int m0, int n0, floatx4 (&acc)[4][4])
{
    const int tid  = threadIdx.x;
    const int w    = tid >> 6, lane = tid & 63;
    const int quad = lane >> 4, l16 = lane & 15;
    const int wm = w >> 1, wn = w & 1;
    const int rsub = lane >> 3;
    const int csub = (lane & 7) * 8;

    const bf16_t* aBase = A + (size_t)(m0 + w * 32 + rsub) * HD_ + csub;
    const bf16_t* bBase = Bt + (size_t)(n0 + w * 32 + rsub) * HD_ + csub;

    for (int kt = 0; kt < HD_; kt += 64) {
        __syncthreads();
        for (int i = 0; i < 4; ++i) {
            const int ar = w * 32 + i * 8;
            async_load16(aBase + (size_t)i * 8 * HD_ + kt, As + ar * 64 + lane * 8);
            async_load16(bBase + (size_t)i * 8 * HD_ + kt, Bs + ar * 64 + lane * 8);
        }
        __syncthreads();
        for (int ks = 0; ks < 2; ++ks) {
            bf16x8 af[4], bf[4];
            for (int mi = 0; mi < 4; ++mi)
                af[mi] = *(const bf16x8*)&As[(wm * 64 + mi * 16 + l16) * 64 + ks * 32 + quad * 8];
            for (int ni = 0; ni < 4; ++ni)
                bf[ni] = *(const bf16x8*)&Bs[(wn * 64 + ni * 16 + l16) * 64 + ks * 32 + quad * 8];
            for (int mi = 0; mi < 4; ++mi)
                for (int ni = 0; ni < 4; ++ni)
                    acc[mi][ni] = __builtin_amdgcn_mfma_f32_16x16x32_bf16(
                        af[mi], bf[ni], acc[mi][ni], 0, 0, 0);
        }
    }
}

// ---------------- fused QKV projection (z = 0:Q, 1:K, 2:V) -----------------
// K' layout: nh | kvb=l>>5 | s=d>>4 | (l&31)+32*((d>>3)&1) | d&7
// V' layout (kv bits 2<->3 swapped so P needs no lane shuffles):
//   nh | (l>>6)*2+(d>>5) | (l>>4)&3 | (d&31)+32*((l>>2)&1) | (l&3)+4*((l>>3)&1)
// XCD swizzle (T1): 1152 blocks = 8 XCDs x 144. Without it, the 6 blocks
// sharing an A row-panel land on 6 different XCDs and each XCD's L2 streams
// ~all of A; with it each XCD owns 24 consecutive panels (~4.7 MB, resident).
struct QKVArgs {
    const bf16_t* Bt[3];
    const float* bias[3];
    void* out[3];
};
__global__ __launch_bounds__(256) void gemm_qkv_kernel(const bf16_t* __restrict__ A, QKVArgs p)
{
    __shared__ __align__(16) bf16_t S[2 * 128 * 64];   // As | Bs, reused as out-stage
    const int lb = blockIdx.x + gridDim.x * blockIdx.y
                 + gridDim.x * gridDim.y * blockIdx.z;          // 0..1151
    const int sidx = (lb & 7) * 144 + (lb >> 3);                // bijective
    const int z = sidx / 384;
    const int rem = sidx - z * 384;
    const int m0 = (rem / 6) * 128, n0 = (rem % 6) * 128;

    floatx4 acc[4][4] = {};
    gemm_tile128(A, p.Bt[z], S, S + 8192, m0, n0, acc);

    const int tid  = threadIdx.x;
    const int lane = tid & 63;
    const int quad = lane >> 4, l16 = lane & 15;
    const int w    = tid >> 6;
    const int wm = w >> 1, wn = w & 1;
    const float scale = (z == 0) ? QSCALE : 1.0f;
    const float* bias = p.bias[z];

    __syncthreads();   // all waves done reading As/Bs
    for (int ni = 0; ni < 4; ++ni) {
        const int dl = ni * 16 + l16;
        const float bv = bias[n0 + wn * 64 + dl];
        for (int mi = 0; mi < 4; ++mi) {
            for (int r = 0; r < 4; ++r) {
                const int ll = wm * 64 + mi * 16 + quad * 4 + r;
                const float val = (acc[mi][ni][r] + bv) * scale;
                int off;
                if (z == 0)
                    off = ll * 64 + dl;
                else if (z == 1)
                    off = ((ll >> 5) * 4 + (dl >> 4)) * 512
                        + ((ll & 31) + 32 * ((dl >> 3) & 1)) * 8 + (dl & 7);
                else
                    off = (((ll >> 6) * 2 + (dl >> 5)) * 4 + ((ll >> 4) & 3)) * 512
                        + ((dl & 31) + 32 * ((ll >> 2) & 1)) * 8
                        + ((ll & 3) + 4 * ((ll >> 3) & 1));
                if (z == 2) ((f16_t*)S)[wn * 8192 + off] = (f16_t)val;
                else        S[wn * 8192 + off] = (bf16_t)val;
            }
        }
    }
    __syncthreads();

    // copy out: 16 KB per head, fully contiguous in global
    const int ht = tid >> 7, idx = tid & 127;
    const int nn = m0 >> 12, l0 = m0 & 4095;
    const int h = (n0 >> 6) + ht;
    char* dstBase;
    if (z == 0)
        dstBase = (char*)p.out[0] + (((size_t)(nn * HH + h) * LL + l0) * 64) * 2;
    else if (z == 1)
        dstBase = (char*)p.out[1] + ((size_t)(nn * HH + h) * KVSTRIDE + (size_t)(l0 >> 5) * 2048) * 2;
    else
        dstBase = (char*)p.out[2] + ((size_t)(nn * HH + h) * KVSTRIDE + (size_t)(l0 >> 6) * 4096) * 2;
    const bf16_t* srcB = S + ht * 8192;
    for (int c = 0; c < 8; ++c) {
        const int cc = (c + idx) & 7;   // bank-rotated: conflict-minimal b128 reads
        *(bf16x8*)(dstBase + (idx * 64 + cc * 8) * 2) = *(const bf16x8*)(srcB + idx * 64 + cc * 8);
    }
}

// ---------------- output projection (fp32 out), 128x64 tiles ---------------
// R5/R7-validated shape: 768 blocks (3/CU), single-buffered (dbuf regressed
// 12 us in R8 -- short compute phase can't cover staging; reverted).
// + XCD swizzle: 768 = 8 x 96, each XCD owns 8 consecutive A row-panels.
__global__ __launch_bounds__(256) void gemm_o_kernel(
    const bf16_t* __restrict__ A, const bf16_t* __restrict__ Bt,
    const float* __restrict__ bias, float* __restrict__ Cout)
{
    __shared__ __align__(16) bf16_t As[128 * 64];   // 16 KB
    __shared__ __align__(16) bf16_t Bs[64 * 64];    // 8 KB
    const int lb = blockIdx.x + gridDim.x * blockIdx.y;         // 0..767
    const int sidx = (lb & 7) * 96 + (lb >> 3);                 // bijective
    const int m0 = (sidx / 12) * 128, n0 = (sidx % 12) * 64;

    const int tid  = threadIdx.x;
    const int w    = tid >> 6, lane = tid & 63;
    const int quad = lane >> 4, l16 = lane & 15;
    const int rsub = lane >> 3;
    const int csub = (lane & 7) * 8;

    const bf16_t* aBase = A + (size_t)(m0 + w * 32 + rsub) * HD_ + csub;
    const bf16_t* bBase = Bt + (size_t)(n0 + w * 16 + rsub) * HD_ + csub;

    floatx4 acc[2][4] = {};

    for (int kt = 0; kt < HD_; kt += 64) {
        __syncthreads();
        #pragma unroll
        for (int i = 0; i < 4; ++i)
            async_load16(aBase + (size_t)i * 8 * HD_ + kt, As + (w * 32 + i * 8) * 64 + lane * 8);
        #pragma unroll
        for (int i = 0; i < 2; ++i)
            async_load16(bBase + (size_t)i * 8 * HD_ + kt, Bs + (w * 16 + i * 8) * 64 + lane * 8);
        __syncthreads();
        #pragma unroll
        for (int ks = 0; ks < 2; ++ks) {
            bf16x8 af[2], bf[4];
            #pragma unroll
            for (int mi = 0; mi < 2; ++mi)
                af[mi] = *(const bf16x8*)&As[(w * 32 + mi * 16 + l16) * 64 + ks * 32 + quad * 8];
            #pragma unroll
            for (int ni = 0; ni < 4; ++ni)
                bf[ni] = *(const bf16x8*)&Bs[(ni * 16 + l16) * 64 + ks * 32 + quad * 8];
            #pragma unroll
            for (int mi = 0; mi < 2; ++mi)
                #pragma unroll
                for (int ni = 0; ni < 4; ++ni)
                    acc[mi][ni] = __builtin_amdgcn_mfma_f32_16x16x32_bf16(
                        af[mi], bf[ni], acc[mi][ni], 0, 0, 0);
        }
    }

    #pragma unroll
    for (int ni = 0; ni < 4; ++ni) {
        const int col = n0 + ni * 16 + l16;
        const float bv = bias[col];
        #pragma unroll
        for (int mi = 0; mi < 2; ++mi)
            #pragma unroll
            for (int r = 0; r < 4; ++r) {
                const int row = m0 + w * 32 + mi * 16 + quad * 4 + r;
                Cout[(size_t)row * HD_ + col] = acc[mi][ni][r] + bv;
            }
    }
}

// ---------------- flash attention: S(t+1) || P(t) double pipeline ----------
// (round-2 validated kernel: ~108-113 us, MfmaUtil 43-46, conflicts 147K,
// VGPR 80 -- confirmed 5x. Frozen.)
__global__ __launch_bounds__(256, 3) void attn_kernel(
    const bf16_t* __restrict__ qg, const bf16_t* __restrict__ kf,
    const f16_t* __restrict__ vf, bf16_t* __restrict__ og)
{
    __shared__ union {
        struct {
            bf16_t Ks[2][4096];   // 2 x 8 KB tiles
            f16_t  Vs[4][4096];   // 4 x 8 KB tiles
        } s;                      // 48 KB -> 3 blocks/CU
        bf16_t OT[128 * 72];      // epilogue (18 KB)
    } u;

    const int tid = threadIdx.x;
    const int w = tid >> 6, lane = tid & 63;
    const int l32 = lane & 31, hi = lane >> 5;

    // XCD-aware remap: 768 blocks = 8 XCDs x 96 (bijective). Each XCD owns
    // 3 consecutive nh -> its 3 MB KV working set stays L2-resident.
    const int lb = blockIdx.y * gridDim.x + blockIdx.x;
    const int idx = (lb & 7) * 96 + (lb >> 3);
    const int nh = idx >> 5;
    const int qt0 = (idx & 31) * 128;
    const int nIdx = nh / HH, hIdx = nh % HH;

    // Q B-frags: lane (q=l32, hi) holds Q[qrow][s*16 + hi*8 + j]
    bf16x8 qfrag[4];
    {
        const bf16_t* qp = qg + ((size_t)nh * LL + qt0 + w * 32 + l32) * DD + hi * 8;
        for (int s = 0; s < 4; ++s) qfrag[s] = *(const bf16x8*)(qp + s * 16);
    }

    // DMA: wave w stages chunks {2w, 2w+1} of each 8-chunk (8 KB) tile
    const bf16_t* ksrc = kf + (size_t)nh * KVSTRIDE + (2 * w) * 512 + lane * 8;
    const f16_t*  vsrc = vf + (size_t)nh * KVSTRIDE + (2 * w) * 512 + lane * 8;
    const int soff0 = (2 * w) * 512 + lane * 8;
    const int soff1 = (2 * w + 1) * 512 + lane * 8;

    floatx16 oacc[2] = {};
    float rs = 0.f;
    floatx16 sA0, sA1, sB0, sB1;   // QK accumulators, A/B alternate per step

#define STAGE_K(kb) { async_load16(ksrc, &u.s.Ks[kb][soff0]);                 \
                      async_load16(ksrc + 512, &u.s.Ks[kb][soff1]);           \
                      ksrc += 4096; }
#define STAGE_V(vb) { async_load16(vsrc, &u.s.Vs[vb][soff0]);                 \
                      async_load16(vsrc + 512, &u.s.Vs[vb][soff1]);           \
                      vsrc += 4096; }

// S: QK^T for one tile from K ring slot kr -> (SD0: kv rows 0..31, SD1: 32..63)
#define SSTEP(SD0, SD1, kr)                                                   \
    {                                                                         \
        SD0 = (floatx16){}; SD1 = (floatx16){};                               \
        _Pragma("unroll")                                                     \
        for (int s = 0; s < 4; ++s) {                                         \
            bf16x8 a0 = *(const bf16x8*)&u.s.Ks[kr][s * 512 + lane * 8];      \
            SD0 = __builtin_amdgcn_mfma_f32_32x32x16_bf16(a0, qfrag[s], SD0, 0, 0, 0); \
            bf16x8 a1 = *(const bf16x8*)&u.s.Ks[kr][(4 + s) * 512 + lane * 8]; \
            SD1 = __builtin_amdgcn_mfma_f32_32x32x16_bf16(a1, qfrag[s], SD1, 0, 0, 0); \
        }                                                                     \
    }

// P half: softmax (exp2, row-sum) + PV MFMA for one kvb half from V slot vp
#define PHALF(SC, vp, kvb)                                                    \
    _Pragma("unroll")                                                         \
    for (int sub = 0; sub < 2; ++sub) {                                       \
        float p[8];                                                           \
        _Pragma("unroll")                                                     \
        for (int i = 0; i < 8; ++i)                                           \
            p[i] = __builtin_amdgcn_exp2f(SC[sub * 8 + i]);                   \
        rs += ((p[0] + p[1]) + (p[2] + p[3])) + ((p[4] + p[5]) + (p[6] + p[7])); \
        f16x2 ab = pkrtz(p[0], p[1]), cd = pkrtz(p[2], p[3]);                 \
        f16x2 ef = pkrtz(p[4], p[5]), gh = pkrtz(p[6], p[7]);                 \
        f16x4 lo4 = __builtin_shufflevector(ab, cd, 0, 1, 2, 3);              \
        f16x4 hi4 = __builtin_shufflevector(ef, gh, 0, 1, 2, 3);              \
        f16x8 pf = __builtin_shufflevector(lo4, hi4, 0, 1, 2, 3, 4, 5, 6, 7); \
        const int kstep = (kvb) * 2 + sub;                                    \
        _Pragma("unroll")                                                     \
        for (int db = 0; db < 2; ++db) {                                      \
            f16x8 av = *(const f16x8*)&u.s.Vs[vp][(db * 4 + kstep) * 512 + lane * 8]; \
            oacc[db] = __builtin_amdgcn_mfma_f32_32x32x16_f16(av, pf, oacc[db], 0, 0, 0); \
        }                                                                     \
    }

// One pipeline step: barrier; issue DMA for tile t+2; S(t+1); P(t).
// doDMA/doS are 0/1 literals; all ring indices compile-time.
#define STEP(doDMA, kw, vw, doS, kr, SD0, SD1, SP0, SP1, vp)                  \
    __syncthreads();                                                          \
    if (doDMA) { STAGE_K(kw); STAGE_V(vw); }                                  \
    __builtin_amdgcn_s_setprio(1);                                            \
    if (doS) SSTEP(SD0, SD1, kr);                                             \
    PHALF(SP0, vp, 0)                                                         \
    PHALF(SP1, vp, 1)                                                         \
    __builtin_amdgcn_s_setprio(0);

    // prologue: stage tiles 0,1; compute S(0)
    STAGE_K(0) STAGE_V(0) STAGE_K(1) STAGE_V(1)
    __syncthreads();
    SSTEP(sA0, sA1, 0);

    // steady state: 15 groups of 4 steps; P(0)..P(59), DMA tiles 2..61
    for (int t = 0; t < 60; t += 4) {
        STEP(1, 0, 2, 1, 1, sB0, sB1, sA0, sA1, 0)   // DMA t+2->K0,V2; S(t+1)<-K1; P(t)<-V0
        STEP(1, 1, 3, 1, 0, sA0, sA1, sB0, sB1, 1)   // DMA t+3->K1,V3; S(t+2)<-K0; P(t+1)<-V1
        STEP(1, 0, 0, 1, 1, sB0, sB1, sA0, sA1, 2)   // DMA t+4->K0,V0; S(t+3)<-K1; P(t+2)<-V2
        STEP(1, 1, 1, 1, 0, sA0, sA1, sB0, sB1, 3)   // DMA t+5->K1,V1; S(t+4)<-K0; P(t+3)<-V3
    }
    // tail: t = 60..63 (DMA tiles 62,63; last S is S(63))
    STEP(1, 0, 2, 1, 1, sB0, sB1, sA0, sA1, 0)       // DMA 62->K0,V2; S(61); P(60)
    STEP(1, 1, 3, 1, 0, sA0, sA1, sB0, sB1, 1)       // DMA 63->K1,V3; S(62); P(61)
    STEP(0, 0, 0, 1, 1, sB0, sB1, sA0, sA1, 2)       //               S(63); P(62)
    STEP(0, 0, 0, 0, 0, sA0, sA1, sB0, sB1, 3)       //                      P(63)

#undef STEP
#undef PHALF
#undef SSTEP
#undef STAGE_K
#undef STAGE_V

    // full row sum per q: add the partner half-wave's partial
    rs += __shfl_xor(rs, 32);
    const float rinv = __builtin_amdgcn_rcpf(rs);

    // O^T -> O via LDS transpose, then coalesced store
    __syncthreads();
    for (int db = 0; db < 2; ++db)
        for (int g = 0; g < 4; ++g) {
            bf16x4 o4;
            for (int r = 0; r < 4; ++r)
                o4[r] = (bf16_t)(oacc[db][g * 4 + r] * rinv);
            // d = r + 8g + 4hi + 32db
            *(bf16x4*)&u.OT[(w * 32 + l32) * 72 + db * 32 + hi * 4 + g * 8] = o4;
        }
    __syncthreads();

    const int q = tid >> 1, hf = tid & 1;
    const bf16_t* src = &u.OT[q * 72 + hf * 32];
    bf16x8 r0 = *(const bf16x8*)(src + 0);
    bf16x8 r1 = *(const bf16x8*)(src + 8);
    bf16x8 r2 = *(const bf16x8*)(src + 16);
    bf16x8 r3 = *(const bf16x8*)(src + 24);
    bf16_t* dst = og + ((size_t)nIdx * LL + qt0 + q) * HD_ + hIdx * 64 + hf * 32;
    *(bf16x8*)(dst + 0)  = r0;
    *(bf16x8*)(dst + 8)  = r1;
    *(bf16x8*)(dst + 16) = r2;
    *(bf16x8*)(dst + 24) = r3;
}

extern "C" void kernel_launch(void* const* d_in, const int* in_sizes, int n_in,
                              void* d_out, int out_size, void* d_ws, size_t ws_size,
                              hipStream_t stream) {
    const float* x  = (const float*)d_in[0];
    const float* Wq = (const float*)d_in[1];
    const float* bq = (const float*)d_in[2];
    const float* Wk = (const float*)d_in[3];
    const float* bk = (const float*)d_in[4];
    const float* Wv = (const float*)d_in[5];
    const float* bv = (const float*)d_in[6];
    const float* Wo = (const float*)d_in[7];
    const float* bo = (const float*)d_in[8];

    char* ws = (char*)d_ws;
    const size_t xbytes = (size_t)M_TOT * HD_ * 2;
    const size_t wbytes = (size_t)HD_ * HD_ * 2;

    bf16_t* xb  = (bf16_t*)ws; ws += xbytes;
    bf16_t* wqt = (bf16_t*)ws; ws += wbytes;
    bf16_t* wkt = (bf16_t*)ws; ws += wbytes;
    bf16_t* wvt = (bf16_t*)ws; ws += wbytes;
    bf16_t* wot = (bf16_t*)ws; ws += wbytes;
    bf16_t* qb  = (bf16_t*)ws; ws += xbytes;
    bf16_t* kfb = (bf16_t*)ws; ws += xbytes;
    f16_t*  vfb = (f16_t*)ws;  ws += xbytes;
    bf16_t* ob  = (bf16_t*)ws; ws += xbytes;

    PrepArgs pa;
    pa.x = x; pa.xb = xb;
    pa.W[0] = Wq; pa.W[1] = Wk; pa.W[2] = Wv; pa.W[3] = Wo;
    pa.Wt[0] = wqt; pa.Wt[1] = wkt; pa.Wt[2] = wvt; pa.Wt[3] = wot;
    prep_kernel<<<CVT_BLOCKS + 576, 256, 0, stream>>>(pa);

    QKVArgs qa;
    qa.Bt[0] = wqt; qa.Bt[1] = wkt; qa.Bt[2] = wvt;
    qa.bias[0] = bq; qa.bias[1] = bk; qa.bias[2] = bv;
    qa.out[0] = qb; qa.out[1] = kfb; qa.out[2] = vfb;
    gemm_qkv_kernel<<<dim3(HD_ / 128, M_TOT / 128, 3), 256, 0, stream>>>(xb, qa);

    attn_kernel<<<dim3(LL / 128, NN * HH), 256, 0, stream>>>(qb, kfb, vfb, ob);

    gemm_o_kernel<<<dim3(HD_ / 64, M_TOT / 128), 256, 0, stream>>>(ob, wot, bo, (float*)d_out);
}